// Round 7
// baseline (355.275 us; speedup 1.0000x reference)
//
#include <hip/hip_runtime.h>
#include <hip/hip_bf16.h>

typedef __attribute__((ext_vector_type(8))) short short8;
typedef __attribute__((ext_vector_type(4))) float f32x4;
typedef __attribute__((ext_vector_type(16))) float f32x16;
typedef __attribute__((ext_vector_type(4))) int i32x4;
typedef unsigned short u16;

#define S_LEN 2048
#define D_DIM 2048
#define NHEAD 16
#define HDIM 128
#define M_ROWS 4096

#define MFMA(a,b,c) __builtin_amdgcn_mfma_f32_16x16x32_bf16(a,b,c,0,0,0)
#define MFMA32(a,b,c) __builtin_amdgcn_mfma_f32_32x32x16_bf16(a,b,c,0,0,0)

__device__ __forceinline__ u16 f2bf(float f) {
  union { float f; unsigned u; } v; v.f = f;
  unsigned r = v.u + 0x7fffu + ((v.u >> 16) & 1u);
  return (u16)(r >> 16);
}

__device__ __forceinline__ void async16(void* lds, const void* g) {
  __builtin_amdgcn_global_load_lds(
      (const __attribute__((address_space(1))) unsigned*)g,
      (__attribute__((address_space(3))) unsigned*)lds, 16, 0, 0);
}

__device__ __forceinline__ unsigned cvtpk(float lo, float hi) {
  unsigned r;
  asm("v_cvt_pk_bf16_f32 %0, %1, %2" : "=v"(r) : "v"(lo), "v"(hi));
  return r;
}
__device__ __forceinline__ void plswap(unsigned& x, unsigned& y) {
  asm("v_permlane32_swap_b32 %0, %1" : "+v"(x), "+v"(y));
}

// ---------------- x -> bf16 ----------------
__global__ void k_cvt_x(const float* __restrict__ x, u16* __restrict__ xb) {
  int i = blockIdx.x * 256 + threadIdx.x;
  float4 v = reinterpret_cast<const float4*>(x)[i];
  ushort4 o;
  o.x = f2bf(v.x); o.y = f2bf(v.y); o.z = f2bf(v.z); o.w = f2bf(v.w);
  reinterpret_cast<ushort4*>(xb)[i] = o;
}

// -------- W[k][n] f32 -> Wt[n][k] bf16 (transpose+convert) --------
__global__ void k_cvt_wt(const float* __restrict__ W, u16* __restrict__ Wt) {
  __shared__ u16 tile[32][33];
  int n0 = blockIdx.x * 32, k0 = blockIdx.y * 32;
  int tx = threadIdx.x & 31, ty = threadIdx.x >> 5;
#pragma unroll
  for (int i = 0; i < 4; i++)
    tile[ty + i * 8][tx] = f2bf(W[(size_t)(k0 + ty + i * 8) * D_DIM + n0 + tx]);
  __syncthreads();
#pragma unroll
  for (int i = 0; i < 4; i++)
    Wt[(size_t)(n0 + ty + i * 8) * D_DIM + k0 + tx] = tile[tx][ty + i * 8];
}

// -------- V[b,h,s,d] -> Vt[b,h,d,s] (bf16 transpose) --------
__global__ void k_vtrans(const u16* __restrict__ V, u16* __restrict__ Vt) {
  __shared__ u16 tile[32][33];
  int s0 = blockIdx.x * 32, d0 = blockIdx.y * 32, bh = blockIdx.z;
  const u16* Vp = V + (size_t)bh * S_LEN * HDIM;
  u16* Vtp = Vt + (size_t)bh * HDIM * S_LEN;
  int tx = threadIdx.x & 31, ty = threadIdx.x >> 5;
#pragma unroll
  for (int i = 0; i < 4; i++)
    tile[ty + i * 8][tx] = Vp[(size_t)(s0 + ty + i * 8) * HDIM + d0 + tx];
  __syncthreads();
#pragma unroll
  for (int i = 0; i < 4; i++)
    Vtp[(size_t)(d0 + ty + i * 8) * S_LEN + s0 + tx] = tile[tx][ty + i * 8];
}

// ======== ring-4 deep-pipelined GEMM: C = A[M][K] * Bt[N][K]^T ========
// Tile 256 x BN (BN = NFRAG*64), BK=32 units, 4-slot LDS ring, prefetch
// distance 3 (U(t+3) issued in tile-t body). Unit U(t) = {A[256][32],
// B[BN][32]}; per-thread LPU loads/unit, identical issue order across waves
// and in-order vmcnt retirement -> vmcnt(2*LPU) guarantees U(t) fully
// LDS-resident for ALL waves (2 newer units may be in flight). Tail: LPU,0.
// Rows 64B = 4 x 16B slots; swizzle slot ^= (row>>1)&3 via pre-swizzled
// global source + same XOR on ds_read (involution, rule 21).
template <int NFRAG, int MODE>
__global__ __launch_bounds__(512, 2) void k_gemm3(const u16* __restrict__ A,
                                                  const u16* __restrict__ Bt,
                                                  void* __restrict__ outp,
                                                  const float* __restrict__ fac) {
  constexpr int BN = NFRAG * 64;
  constexpr int AUNIT = 16384;       // 256 rows * 64B
  constexpr int BUNIT = BN * 64;
  constexpr int LPU = 2 + NFRAG / 2; // per-thread loads per unit
  __shared__ __align__(16) char lds[4 * (AUNIT + BUNIT)];
  const int m0 = blockIdx.y * 256, n0 = blockIdx.x * BN;
  const int t = threadIdx.x;
  const int w = t >> 6, l = t & 63;
  const int wr = (w >> 2) * 128, wc = (w & 3) * (BN / 4);
  const int lr = l & 15, lq = l >> 4;
  const char* Ab = (const char*)A;
  const char* Bb = (const char*)Bt;

  f32x4 acc[8][NFRAG] = {};

  auto stage_unit = [&](int tt) {
    const int slot = tt & 3;
#pragma unroll
    for (int j = 0; j < 2; j++) {  // A: 16KB = 2 x 8KB issues
      const int p = j * 8192 + w * 1024 + l * 16;
      const int row = p >> 6, sl = (p >> 4) & 3;
      async16(lds + slot * AUNIT + p,
              Ab + (size_t)(m0 + row) * 4096 + tt * 64 + ((sl ^ ((row >> 1) & 3)) * 16));
    }
#pragma unroll
    for (int j = 0; j < NFRAG / 2; j++) {  // B
      const int p = j * 8192 + w * 1024 + l * 16;
      const int row = p >> 6, sl = (p >> 4) & 3;
      async16(lds + 4 * AUNIT + slot * BUNIT + p,
              Bb + (size_t)(n0 + row) * 4096 + tt * 64 + ((sl ^ ((row >> 1) & 3)) * 16));
    }
  };

  auto compute = [&](int tt) {
    const int slot = tt & 3;
    const char* Ar = lds + slot * AUNIT;
    const char* Br = lds + 4 * AUNIT + slot * BUNIT;
    short8 af[8], bf[NFRAG];
#pragma unroll
    for (int mi = 0; mi < 8; mi++) {
      const int row = wr + mi * 16 + lr;
      af[mi] = *reinterpret_cast<const short8*>(
          Ar + row * 64 + ((lq ^ ((row >> 1) & 3)) * 16));
    }
#pragma unroll
    for (int ni = 0; ni < NFRAG; ni++) {
      const int row = wc + ni * 16 + lr;
      bf[ni] = *reinterpret_cast<const short8*>(
          Br + row * 64 + ((lq ^ ((row >> 1) & 3)) * 16));
    }
    __builtin_amdgcn_s_setprio(1);
#pragma unroll
    for (int mi = 0; mi < 8; mi++)
#pragma unroll
      for (int ni = 0; ni < NFRAG; ni++)
        acc[mi][ni] = MFMA(af[mi], bf[ni], acc[mi][ni]);
    __builtin_amdgcn_s_setprio(0);
  };

  // prologue: 3 units in flight
  stage_unit(0);
  stage_unit(1);
  stage_unit(2);

  const int NT = D_DIM / 32;  // 64
  for (int tt = 0; tt < NT; tt++) {
    if (tt < NT - 2)
      asm volatile("s_waitcnt vmcnt(%0)" :: "n"(2 * LPU) : "memory");
    else if (tt == NT - 2)
      asm volatile("s_waitcnt vmcnt(%0)" :: "n"(LPU) : "memory");
    else
      asm volatile("s_waitcnt vmcnt(0)" ::: "memory");
    __builtin_amdgcn_s_barrier();
    asm volatile("" ::: "memory");
    if (tt + 3 < NT) stage_unit(tt + 3);
    compute(tt);
  }

  // epilogue
#pragma unroll
  for (int mi = 0; mi < 8; mi++) {
#pragma unroll
    for (int ni = 0; ni < NFRAG; ni++) {
#pragma unroll
      for (int r = 0; r < 4; r++) {
        const int row = m0 + wr + mi * 16 + lq * 4 + r;
        const int col = n0 + wc + ni * 16 + lr;
        const float v = acc[mi][ni][r];
        if (MODE == 0) {
          const int mat = col >> 11;
          const int hh = (col >> 7) & 15;
          ((u16*)outp)[(size_t)mat * 8388608 +
                       (((size_t)((row >> 11) * NHEAD + hh)) * S_LEN + (row & 2047)) * HDIM +
                       (col & 127)] = f2bf(v);
        } else {
          ((float*)outp)[(size_t)row * D_DIM + col] = v * (1.0f + 0.1f * fac[row]);
        }
      }
    }
  }
}

// -------- phase projections pq/pk = xb @ Wpq / xb @ Wpk --------
// 256 blocks x 256 thr; block = 16 m-rows; x as bf16x8; W staged in LDS as
// interleaved float2 (one b64 read/k gives both weights, conflict-free).
__global__ __launch_bounds__(256) void k_phase_proj(const u16* __restrict__ xb,
                                                    const float* __restrict__ Wpq,
                                                    const float* __restrict__ Wpk,
                                                    float* __restrict__ pq,
                                                    float* __restrict__ pk) {
  __shared__ u16 xs[16][136];
  __shared__ float2 ws[128][16];
  const int t = threadIdx.x;
  const int m0 = blockIdx.x * 16;
  const int h = t & 15, r = t >> 4;
  float sq = 0.f, sk = 0.f;
  for (int kc = 0; kc < D_DIM; kc += 128) {
    *reinterpret_cast<short8*>(&xs[t >> 4][(t & 15) * 8]) =
        *reinterpret_cast<const short8*>(
            &xb[(size_t)(m0 + (t >> 4)) * D_DIM + kc + (t & 15) * 8]);
#pragma unroll
    for (int j = 0; j < 8; j++) {
      const int idx = j * 256 + t;
      const int k = idx >> 4, hh = idx & 15;
      ws[k][hh] = make_float2(Wpq[(size_t)(kc + k) * NHEAD + hh],
                              Wpk[(size_t)(kc + k) * NHEAD + hh]);
    }
    __syncthreads();
#pragma unroll
    for (int k8 = 0; k8 < 16; k8++) {
      const short8 x8 = *reinterpret_cast<const short8*>(&xs[r][k8 * 8]);
#pragma unroll
      for (int j = 0; j < 8; j++) {
        union { float f; unsigned u; } c;
        c.u = ((unsigned)(u16)x8[j]) << 16;
        const float2 wv = ws[k8 * 8 + j][h];
        sq += c.f * wv.x;
        sk += c.f * wv.y;
      }
    }
    __syncthreads();
  }
  pq[(size_t)(m0 + r) * NHEAD + h] = sq;
  pk[(size_t)(m0 + r) * NHEAD + h] = sk;
}

__device__ __forceinline__ float wave_sum(float v) {
  v += __shfl_xor(v, 1);  v += __shfl_xor(v, 2);  v += __shfl_xor(v, 4);
  v += __shfl_xor(v, 8);  v += __shfl_xor(v, 16); v += __shfl_xor(v, 32);
  return v;
}

// -------- Ck/Sk = sum_s cos/sin(pk) per (b,h) --------
__global__ void k_phase_ck(const float* __restrict__ pk, float* __restrict__ Ck,
                           float* __restrict__ Sk) {
  int bh = blockIdx.x, b = bh >> 4, h = bh & 15;
  float c = 0.f, s = 0.f;
  for (int ss = threadIdx.x; ss < S_LEN; ss += 256) {
    float v = pk[((size_t)b * S_LEN + ss) * NHEAD + h];
    c += cosf(v); s += sinf(v);
  }
  c = wave_sum(c); s = wave_sum(s);
  __shared__ float rc[4], rs[4];
  int wv = threadIdx.x >> 6;
  if ((threadIdx.x & 63) == 0) { rc[wv] = c; rs[wv] = s; }
  __syncthreads();
  if (threadIdx.x == 0) {
    Ck[bh] = rc[0] + rc[1] + rc[2] + rc[3];
    Sk[bh] = rs[0] + rs[1] + rs[2] + rs[3];
  }
}

// -------- phase_mod[m] --------
__global__ void k_phase_mod(const float* __restrict__ pq, const float* __restrict__ Ck,
                            const float* __restrict__ Sk, float* __restrict__ pm) {
  int m = blockIdx.x * 256 + threadIdx.x;
  int b = m >> 11;
  float a = 0.f;
#pragma unroll
  for (int h = 0; h < NHEAD; h++) {
    float v = pq[(size_t)m * NHEAD + h];
    a += cosf(v) * Ck[b * NHEAD + h] + sinf(v) * Sk[b * NHEAD + h];
  }
  pm[m] = a * (1.0f / (S_LEN * NHEAD));
}

// -------- causal flash attention: 4 warps x 32 q-rows, double-buffered K/V --------
// Per tile: vmcnt(0); barrier; issue stage(t+1 -> other buf); compute(t).
// Next tile's DMA flies under compute(t) (T14 depth-1). One barrier/tile.
__global__ __launch_bounds__(256, 2) void k_attn(const u16* __restrict__ Q,
                                                 const u16* __restrict__ K,
                                                 const u16* __restrict__ Vt,
                                                 u16* __restrict__ ctx) {
  const int bh = blockIdx.x;
  const int gy = blockIdx.y;
  const int g = (gy < 8) ? (15 - gy) : (gy - 8);  // pair long/short across dispatch
  const int b = bh >> 4, h = bh & 15;
  const int t = threadIdx.x;
  const int w = t >> 6, l = t & 63;
  const int ln = l & 31, hi = l >> 5;
  const int q0w = g * 128 + w * 32;
  const int qq = q0w + ln;
  const float scale = 0.08838834764831845f;

  const u16* Qp = Q + (size_t)bh * S_LEN * HDIM;
  const char* Kg = (const char*)(K + (size_t)bh * S_LEN * HDIM);
  const char* Vg = (const char*)(Vt + (size_t)bh * HDIM * S_LEN);

  __shared__ __align__(16) char Ks[2][16384];
  __shared__ __align__(16) char Vs[2][16384];

  auto stage = [&](int t64, int buf) {
    const int k0 = t64 * 64;
#pragma unroll
    for (int i = 0; i < 4; i++) {
      const int key = i * 16 + w * 4 + (l >> 4);
      async16(Ks[buf] + i * 4096 + w * 1024,
              Kg + (size_t)(k0 + key) * 256 + (((l & 15) * 16) ^ ((key & 15) << 4)));
      const int d = i * 32 + w * 8 + (l >> 3);
      async16(Vs[buf] + i * 4096 + w * 1024,
              Vg + (size_t)d * (S_LEN * 2) + k0 * 2 + (((l & 7) * 16) ^ ((d & 7) << 4)));
    }
  };

  short8 qf[8];
#pragma unroll
  for (int c = 0; c < 8; c++)
    qf[c] = *reinterpret_cast<const short8*>(Qp + (size_t)qq * HDIM + c * 16 + hi * 8);

  f32x16 o[4];
#pragma unroll
  for (int ds = 0; ds < 4; ds++)
#pragma unroll
    for (int r = 0; r < 16; r++) o[ds][r] = 0.f;
  float mrun = -1e30f, lsum = 0.f;

  const int nt = (g + 1) * 2;
  stage(0, 0);
  for (int t64 = 0; t64 < nt; t64++) {
    const int buf = t64 & 1;
    const int k0 = t64 * 64;
    asm volatile("s_waitcnt vmcnt(0)" ::: "memory");
    __syncthreads();
    if (t64 + 1 < nt) stage(t64 + 1, buf ^ 1);
    if (k0 < q0w + 32) {
      f32x16 s[2];
#pragma unroll
      for (int ks = 0; ks < 2; ks++)
#pragma unroll
        for (int r = 0; r < 16; r++) s[ks][r] = 0.f;
      __builtin_amdgcn_s_setprio(1);
#pragma unroll
      for (int ks = 0; ks < 2; ks++) {
        const int key = ks * 32 + ln;
        const char* kb = Ks[buf] + key * 256;
        const unsigned swzk = (unsigned)((key & 15) << 4);
#pragma unroll
        for (int c = 0; c < 8; c++) {
          const short8 kf = *reinterpret_cast<const short8*>(
              kb + (((unsigned)(c * 32 + hi * 16)) ^ swzk));
          s[ks] = MFMA32(kf, qf[c], s[ks]);
        }
      }
      __builtin_amdgcn_s_setprio(0);
      float p[32];
      float mx = -1e30f;
#pragma unroll
      for (int ks = 0; ks < 2; ks++)
#pragma unroll
        for (int r = 0; r < 16; r++) {
          const int key = k0 + ks * 32 + (r & 3) + 8 * (r >> 2) + 4 * hi;
          const float v = (key <= qq) ? s[ks][r] * scale : -1e30f;
          p[ks * 16 + r] = v;
          mx = fmaxf(mx, v);
        }
      mx = fmaxf(mx, __shfl_xor(mx, 32));
      const float nm = fmaxf(mrun, mx);
      const float f = __expf(mrun - nm);
      float rs = 0.f;
#pragma unroll
      for (int i = 0; i < 32; i++) { p[i] = __expf(p[i] - nm); rs += p[i]; }
      rs += __shfl_xor(rs, 32);
      lsum = lsum * f + rs;
      mrun = nm;
#pragma unroll
      for (int ds = 0; ds < 4; ds++)
#pragma unroll
        for (int r = 0; r < 16; r++) o[ds][r] *= f;
      short8 bfr[4];
#pragma unroll
      for (int sub = 0; sub < 2; sub++) {
#pragma unroll
        for (int half = 0; half < 2; half++) {
          const int pb = sub * 16 + half * 8;
          unsigned X1 = cvtpk(p[pb + 0], p[pb + 1]);
          unsigned X2 = cvtpk(p[pb + 2], p[pb + 3]);
          unsigned Y1 = cvtpk(p[pb + 4], p[pb + 5]);
          unsigned Y2 = cvtpk(p[pb + 6], p[pb + 7]);
          plswap(X1, Y1);
          plswap(X2, Y2);
          i32x4 bw;
          bw[0] = (int)X1; bw[1] = (int)X2; bw[2] = (int)Y1; bw[3] = (int)Y2;
          bfr[sub * 2 + half] = __builtin_bit_cast(short8, bw);
        }
      }
      __builtin_amdgcn_s_setprio(1);
#pragma unroll
      for (int ds = 0; ds < 4; ds++) {
        const int d = ds * 32 + ln;
        const char* vb = Vs[buf] + d * 128;
        const unsigned swzv = (unsigned)((d & 7) << 4);
#pragma unroll
        for (int slot = 0; slot < 4; slot++) {
          const short8 vf = *reinterpret_cast<const short8*>(
              vb + (((unsigned)(slot * 32 + hi * 16)) ^ swzv));
          o[ds] = MFMA32(vf, bfr[slot], o[ds]);
        }
      }
      __builtin_amdgcn_s_setprio(0);
    }
  }

  const float rl = 1.0f / lsum;
#pragma unroll
  for (int ds = 0; ds < 4; ds++) {
#pragma unroll
    for (int rq = 0; rq < 4; rq++) {
      const int d = ds * 32 + 8 * rq + 4 * hi;
      ushort4 pk4;
      pk4.x = f2bf(o[ds][rq * 4 + 0] * rl);
      pk4.y = f2bf(o[ds][rq * 4 + 1] * rl);
      pk4.z = f2bf(o[ds][rq * 4 + 2] * rl);
      pk4.w = f2bf(o[ds][rq * 4 + 3] * rl);
      *reinterpret_cast<ushort4*>(ctx + ((size_t)(b * S_LEN + qq)) * D_DIM + h * HDIM + d) = pk4;
    }
  }
}

extern "C" void kernel_launch(void* const* d_in, const int* in_sizes, int n_in,
                              void* d_out, int out_size, void* d_ws, size_t ws_size,
                              hipStream_t stream) {
  const float* x   = (const float*)d_in[0];
  const float* Wq  = (const float*)d_in[1];
  const float* Wk  = (const float*)d_in[2];
  const float* Wv  = (const float*)d_in[3];
  const float* Wo  = (const float*)d_in[4];
  const float* Wpq = (const float*)d_in[5];
  const float* Wpk = (const float*)d_in[6];

  char* ws = (char*)d_ws;
  u16* xb   = (u16*)(ws + 0);            // 16 MB  x bf16 [4096][2048]
  u16* Wqt  = (u16*)(ws + 16777216);     // 8 MB each, transposed bf16 (Wq,Wk,Wv contiguous)
  u16* Wkt  = (u16*)(ws + 25165824);
  u16* Wvt  = (u16*)(ws + 33554432);
  u16* Wot  = (u16*)(ws + 41943040);
  u16* Qb   = (u16*)(ws + 50331648);     // [b,h,s,d] bf16 (Q,K,V contiguous)
  u16* Kb   = (u16*)(ws + 67108864);
  u16* Vb   = (u16*)(ws + 83886080);     // V, later reused as ctx
  u16* Vt   = (u16*)(ws + 100663296);    // [b,h,d,s] bf16
  float* pq = (float*)(ws + 117440512);
  float* pk = (float*)(ws + 117702656);
  float* Ck = (float*)(ws + 117964800);
  float* Sk = (float*)(ws + 117964928);
  float* pm = (float*)(ws + 117965056);

  k_cvt_x<<<dim3(M_ROWS * D_DIM / 1024), 256, 0, stream>>>(x, xb);
  k_cvt_wt<<<dim3(64, 64), 256, 0, stream>>>(Wq, Wqt);
  k_cvt_wt<<<dim3(64, 64), 256, 0, stream>>>(Wk, Wkt);
  k_cvt_wt<<<dim3(64, 64), 256, 0, stream>>>(Wv, Wvt);
  k_cvt_wt<<<dim3(64, 64), 256, 0, stream>>>(Wo, Wot);

  // fused QKV projection: Bt = [Wqt;Wkt;Wvt] = [6144][2048], 256x256 tiles
  k_gemm3<4, 0><<<dim3(24, 16), 512, 0, stream>>>(xb, Wqt, Qb, nullptr);

  k_vtrans<<<dim3(64, 4, 32), 256, 0, stream>>>(Vb, Vt);

  k_phase_proj<<<dim3(256), 256, 0, stream>>>(xb, Wpq, Wpk, pq, pk);
  k_phase_ck<<<dim3(32), 256, 0, stream>>>(pk, Ck, Sk);
  k_phase_mod<<<dim3(16), 256, 0, stream>>>(pq, Ck, Sk, pm);

  k_attn<<<dim3(32, 16), 256, 0, stream>>>(Qb, Kb, Vt, Vb /*ctx*/);

  // O-proj: 256x128 tiles -> grid 16x16 = 256 blocks (all CUs busy)
  k_gemm3<2, 1><<<dim3(16, 16), 512, 0, stream>>>(Vb /*ctx*/, Wot, (void*)d_out, pm);
}